// Round 1
// baseline (935.944 us; speedup 1.0000x reference)
//
#include <hip/hip_runtime.h>
#include <math.h>

#define N_IN 28
#define N_MID 256
#define N_OUT 28
#define SEQ 28
#define BATCH 4096
#define G3 (3 * N_MID)   // 768

#define BR 16            // batch rows per block
#define THREADS 512      // 2 halves of 256 threads; half handles 8 rows x 256 cols

// Prep: transpose w_hh [768][256] -> w_t [256][768]  (k-major, coalesced col reads)
//       transpose w_ih [768][28]  -> wi_t [28][768]
__global__ void transpose_w(const float* __restrict__ w_hh,
                            const float* __restrict__ w_ih,
                            float* __restrict__ w_t,
                            float* __restrict__ wi_t) {
    int idx = blockIdx.x * 256 + threadIdx.x;
    if (idx < G3 * N_MID) {
        int g = idx / N_MID, k = idx % N_MID;
        w_t[k * G3 + g] = w_hh[idx];
    }
    if (idx < G3 * N_IN) {
        int g = idx / N_IN, i = idx % N_IN;
        wi_t[i * G3 + g] = w_ih[idx];
    }
}

__global__ __launch_bounds__(THREADS) void gru_fused(
    const float* __restrict__ x,     // [B][T][N_IN]
    const float* __restrict__ w_t,   // [N_MID][G3] transposed w_hh
    const float* __restrict__ wi_t,  // [N_IN][G3] transposed w_ih
    const float* __restrict__ b_ih,  // [G3]
    const float* __restrict__ b_hh,  // [G3]
    const float* __restrict__ fc_w,  // [N_OUT][N_MID]
    const float* __restrict__ fc_b,  // [N_OUT]
    float* __restrict__ out)         // [B][N_OUT]
{
    __shared__ float h_s[BR][N_MID];   // 16 KB
    __shared__ float x_s[BR][N_IN];    // current timestep inputs

    const int tid = threadIdx.x;
    const int c  = tid & 255;          // hidden column this thread owns
    const int r0 = (tid >> 8) * 8;     // first of the 8 rows this thread handles
    const int row_base = blockIdx.x * BR;

    // zero h
    for (int i = tid; i < BR * N_MID; i += THREADS) ((float*)h_s)[i] = 0.0f;

    // per-column biases (hoisted out of the t-loop)
    const float bir = b_ih[c],            biz = b_ih[N_MID + c],  bin = b_ih[2 * N_MID + c];
    const float bhr = b_hh[c],            bhz = b_hh[N_MID + c],  bhn = b_hh[2 * N_MID + c];

    __syncthreads();

    for (int t = 0; t < SEQ; ++t) {
        // stage x[row_base .. +BR][t][:]
        for (int i = tid; i < BR * N_IN; i += THREADS) {
            int r = i / N_IN, ii = i - r * N_IN;
            x_s[r][ii] = x[(size_t)(row_base + r) * (SEQ * N_IN) + t * N_IN + ii];
        }
        __syncthreads();

        float xr[8], xz[8], xn[8], hr[8], hz[8], hn[8];
        #pragma unroll
        for (int r = 0; r < 8; ++r) { xr[r]=0.f; xz[r]=0.f; xn[r]=0.f; hr[r]=0.f; hz[r]=0.f; hn[r]=0.f; }

        // ---- input projection (28-dot), w reads coalesced, x broadcast from LDS
        #pragma unroll 4
        for (int i = 0; i < N_IN; ++i) {
            float wr = wi_t[i * G3 + c];
            float wz = wi_t[i * G3 + N_MID + c];
            float wn = wi_t[i * G3 + 2 * N_MID + c];
            #pragma unroll
            for (int r = 0; r < 8; ++r) {
                float xv = x_s[r0 + r][i];
                xr[r] = fmaf(xv, wr, xr[r]);
                xz[r] = fmaf(xv, wz, xz[r]);
                xn[r] = fmaf(xv, wn, xn[r]);
            }
        }

        // ---- hidden projection (256-dot): h via ds_read_b128 broadcast, w coalesced
        #pragma unroll 2
        for (int k4 = 0; k4 < N_MID / 4; ++k4) {
            float4 hv[8];
            #pragma unroll
            for (int r = 0; r < 8; ++r)
                hv[r] = *(const float4*)&h_s[r0 + r][k4 * 4];
            #pragma unroll
            for (int kk = 0; kk < 4; ++kk) {
                int k = k4 * 4 + kk;
                float wr = w_t[k * G3 + c];
                float wz = w_t[k * G3 + N_MID + c];
                float wn = w_t[k * G3 + 2 * N_MID + c];
                #pragma unroll
                for (int r = 0; r < 8; ++r) {
                    float hvv = (kk == 0) ? hv[r].x : (kk == 1) ? hv[r].y : (kk == 2) ? hv[r].z : hv[r].w;
                    hr[r] = fmaf(hvv, wr, hr[r]);
                    hz[r] = fmaf(hvv, wz, hz[r]);
                    hn[r] = fmaf(hvv, wn, hn[r]);
                }
            }
        }

        __syncthreads();   // all dot-reads of h_s done before anyone writes

        #pragma unroll
        for (int r = 0; r < 8; ++r) {
            float rg = 1.0f / (1.0f + __expf(-(xr[r] + bir + hr[r] + bhr)));
            float zg = 1.0f / (1.0f + __expf(-(xz[r] + biz + hz[r] + bhz)));
            float ng = tanhf(xn[r] + bin + rg * (hn[r] + bhn));
            float hold = h_s[r0 + r][c];             // this thread exclusively owns (r, c)
            h_s[r0 + r][c] = (1.0f - zg) * ng + zg * hold;
        }
        __syncthreads();
    }

    // ---- FC epilogue: out[r][o] = h_s[r][:] . fc_w[o][:] + fc_b[o]
    for (int p = tid; p < BR * N_OUT; p += THREADS) {
        int r = p / N_OUT, o = p - r * N_OUT;
        float acc = fc_b[o];
        #pragma unroll 4
        for (int k = 0; k < N_MID; ++k)
            acc = fmaf(h_s[r][k], fc_w[o * N_MID + k], acc);
        out[(size_t)(row_base + r) * N_OUT + o] = acc;
    }
}

extern "C" void kernel_launch(void* const* d_in, const int* in_sizes, int n_in,
                              void* d_out, int out_size, void* d_ws, size_t ws_size,
                              hipStream_t stream) {
    const float* x    = (const float*)d_in[0];
    const float* w_ih = (const float*)d_in[1];
    const float* w_hh = (const float*)d_in[2];
    const float* b_ih = (const float*)d_in[3];
    const float* b_hh = (const float*)d_in[4];
    const float* fc_w = (const float*)d_in[5];
    const float* fc_b = (const float*)d_in[6];
    float* out  = (float*)d_out;

    float* w_t  = (float*)d_ws;          // [256][768] = 786 KB
    float* wi_t = w_t + N_MID * G3;      // [28][768]  =  86 KB

    hipLaunchKernelGGL(transpose_w, dim3(768), dim3(256), 0, stream,
                       w_hh, w_ih, w_t, wi_t);
    hipLaunchKernelGGL(gru_fused, dim3(BATCH / BR), dim3(THREADS), 0, stream,
                       x, w_t, wi_t, b_ih, b_hh, fc_w, fc_b, out);
}